// Round 11
// baseline (812.481 us; speedup 1.0000x reference)
//
#include <hip/hip_runtime.h>

// GLA forward. Structure:
//  - MPGA collapses: fm = mask ? fg : (Wv_f @ mean(bg) + bv_f)
//  - live patches (3x3 mask window == 0): GAP energy uniform ->
//    ck = (gamma/9) * Vg window, L2-normalized.
//  - compaction: only nlive rows flow through gemm1/box/softmax/gemm2.
//  - GEMMs: split-bf16 MFMA (hi/lo, 3 products) on v_mfma_f32_16x16x32_bf16.
//  - NEW: if ws_size allows, att is materialized TRANSPOSED (attT[xy][n],
//    hi/lo planes) by k_applyT; k_gemmB2 then stages A and B identically to
//    k_gemmA (2 barriers/k-step, no in-LDS transpose). Fallback = packed path.

#define BSZ 2
#define C 64
#define WD 64
#define WH 4096
#define PW 66
#define PP 4356
#define KC 576
#define NP 4096

typedef unsigned short u16;
typedef unsigned int u32;
typedef short bf16x8 __attribute__((ext_vector_type(8)));
typedef float f32x4 __attribute__((ext_vector_type(4)));

__device__ inline u16 bf16_rne(float x) {
  unsigned u = __float_as_uint(x);
  return (u16)((u + 0x7FFFu + ((u >> 16) & 1u)) >> 16);
}
__device__ inline float bf16_tof(u16 h) { return __uint_as_float(((unsigned)h) << 16); }
__device__ inline void split2(float x, u16& h, u16& l) {
  h = bf16_rne(x);
  l = bf16_rne(x - bf16_tof(h));
}
__device__ inline u32 pack2(float x) {
  u16 h, l;
  split2(x, h, l);
  return ((u32)h << 16) | (u32)l;
}

// ---------------- prep ----------------

__global__ void k_mu(const float* __restrict__ fg, const float* __restrict__ mask,
                     float* __restrict__ mu) {
  int bc = blockIdx.x;
  int b = bc >> 6;
  const float* f = fg + (size_t)bc * WH;
  const float* mk = mask + (size_t)b * WH;
  float sum = 0.f;
  for (int i = threadIdx.x; i < WH; i += 256) sum += f[i] * (1.f - mk[i]);
  __shared__ float red[256];
  red[threadIdx.x] = sum;
  __syncthreads();
  for (int s = 128; s > 0; s >>= 1) {
    if (threadIdx.x < s) red[threadIdx.x] += red[threadIdx.x + s];
    __syncthreads();
  }
  if (threadIdx.x == 0) mu[bc] = red[0] / (float)WH;
}

__global__ void k_vmean(const float* __restrict__ Wv_f, const float* __restrict__ bv_f,
                        const float* __restrict__ mu, float* __restrict__ vmean) {
  int t = threadIdx.x;
  int b = t >> 6, c = t & 63;
  float acc = bv_f[c];
  for (int cc = 0; cc < C; ++cc) acc += Wv_f[c * C + cc] * mu[b * C + cc];
  vmean[t] = acc;
}

__global__ void k_fm(const float* __restrict__ fg, const float* __restrict__ mask,
                     const float* __restrict__ vmean, float* __restrict__ fm) {
  int idx = blockIdx.x * 256 + threadIdx.x;
  if (idx >= BSZ * C * WH) return;
  int b = idx >> 18;
  int c = (idx >> 12) & 63;
  int pos = idx & (WH - 1);
  float m = mask[b * WH + pos];
  fm[idx] = fg[idx] * m + (1.f - m) * vmean[b * C + c];
}

// bgp[b][pos][c] = padded background + 1e-7
__global__ void k_bgpT(const float* __restrict__ fg, const float* __restrict__ mask,
                       float* __restrict__ bgp) {
  int b = blockIdx.y, xp = blockIdx.x;
  float* out = bgp + ((size_t)b * PP + (size_t)xp * PW) * C;
  int t = threadIdx.x;
  __shared__ float tile[64][65];
  int xi = xp - 1;
  if (xi >= 0 && xi < WD) {
    const float* fgb = fg + (size_t)b * C * WH + (size_t)xi * WD;
    const float* mkb = mask + (size_t)b * WH + (size_t)xi * WD;
    for (int i = t; i < 64 * 64; i += 256) {
      int c = i >> 6, y = i & 63;
      tile[c][y] = fgb[(size_t)c * WH + y] * (1.f - mkb[y]);
    }
  }
  __syncthreads();
  for (int i = t; i < PW * C; i += 256) {
    int yp = i >> 6, c = i & 63;
    float v = 1e-7f;
    int yj = yp - 1;
    if (xi >= 0 && xi < WD && yj >= 0 && yj < WD) v += tile[c][yj];
    out[(size_t)yp * C + c] = v;
  }
}

// Vg[b][pos][o] = Wv_p @ bgp[pos,:] + bv_p
__global__ void k_vgT(const float* __restrict__ bgp, const float* __restrict__ Wv_p,
                      const float* __restrict__ bv_p, float* __restrict__ Vg) {
  __shared__ float Wt[64][65];
  __shared__ float bgl[4][64];
  int t = threadIdx.x;
  for (int i = t; i < 4096; i += 256) Wt[i & 63][i >> 6] = Wv_p[i];
  int pos0 = blockIdx.x * 4;
  {
    int p2 = t >> 6, c = t & 63;
    int gp = pos0 + p2;
    bgl[p2][c] = (gp < BSZ * PP) ? bgp[(size_t)gp * C + c] : 0.f;
  }
  __syncthreads();
  int pi = t >> 6, o = t & 63;
  int gpos = pos0 + pi;
  if (gpos < BSZ * PP) {
    float acc = bv_p[o];
    for (int c = 0; c < 64; ++c) acc += Wt[c][o] * bgl[pi][c];
    Vg[(size_t)gpos * C + o] = acc;
  }
}

// mmf[b][n] = 1 if 3x3 mask window all zero
__global__ void k_mmf(const float* __restrict__ mask, float* __restrict__ mmf) {
  int idx = blockIdx.x * 256 + threadIdx.x;
  if (idx >= BSZ * NP) return;
  int b = idx >> 12, n = idx & 4095;
  int x = n >> 6, y = n & 63;
  float z = 0.f;
  for (int di = -1; di <= 1; ++di)
    for (int dj = -1; dj <= 1; ++dj) {
      int xi = x + di, yj = y + dj;
      if (xi >= 0 && xi < WD && yj >= 0 && yj < WD) z += mask[b * WH + xi * WD + yj];
    }
  mmf[idx] = (z == 0.f) ? 1.f : 0.f;
}

__global__ void k_scan(const float* __restrict__ mmf, int* __restrict__ lividx,
                       int* __restrict__ nliv) {
  int b = blockIdx.x, t = threadIdx.x;
  const float* mm = mmf + (size_t)b * NP;
  int* li = lividx + (size_t)b * NP;
  __shared__ int cnt[256];
  int loc[16];
  int c = 0;
#pragma unroll
  for (int i = 0; i < 16; ++i) {
    int lv = (mm[t * 16 + i] != 0.f) ? 1 : 0;
    loc[i] = lv;
    c += lv;
  }
  cnt[t] = c;
  __syncthreads();
  for (int s = 1; s < 256; s <<= 1) {
    int v = (t >= s) ? cnt[t - s] : 0;
    __syncthreads();
    cnt[t] += v;
    __syncthreads();
  }
  int base = cnt[t] - c;
#pragma unroll
  for (int i = 0; i < 16; ++i)
    if (loc[i]) li[base++] = t * 16 + i;
  int nl = cnt[255];
  if (t == 0) nliv[b] = nl;
  for (int i = nl + t; i < NP; i += 256) li[i] = 0;
}

// live-patch ck: (gamma/9)*Vg window, L2-normalized -> Akc hi/lo [nc][KC]
__global__ void k_ck(const float* __restrict__ Vg, const int* __restrict__ lividx,
                     const int* __restrict__ nliv, const float* __restrict__ gamma,
                     u16* __restrict__ AkcH, u16* __restrict__ AkcL) {
  int b = blockIdx.y, nc = blockIdx.x;
  if (nc >= nliv[b]) return;
  int n = lividx[(size_t)b * NP + nc];
  int x = n >> 6, y = n & 63;
  int c = threadIdx.x;
  const float* vg = Vg + (size_t)b * PP * C;
  float g9 = gamma[0] * (1.f / 9.f);
  float o[9];
  float ss = 0.f;
#pragma unroll
  for (int p = 0; p < 9; ++p) {
    int di = p / 3, dj = p % 3;
    float v = g9 * vg[(size_t)((x + di) * PW + (y + dj)) * C + c];
    o[p] = v;
    ss += v * v;
  }
#pragma unroll
  for (int off = 32; off > 0; off >>= 1) ss += __shfl_down(ss, off, 64);
  ss = __shfl(ss, 0, 64);
  float rn = 1.f / sqrtf(ss);
  u16* ph = AkcH + ((size_t)b * NP + nc) * KC + c * 9;
  u16* pl = AkcL + ((size_t)b * NP + nc) * KC + c * 9;
#pragma unroll
  for (int p = 0; p < 9; ++p) {
    u16 h, l;
    split2(o[p] * rn, h, l);
    ph[p] = h;
    pl[p] = l;
  }
}

// Akc [NP][KC] -> AkT [KC][NP] (hi/lo)
__global__ void k_trA(const u16* __restrict__ Sh, const u16* __restrict__ Sl,
                      u16* __restrict__ Dh, u16* __restrict__ Dl) {
  __shared__ __align__(16) u16 tile[64][72];
  int x0 = blockIdx.x * 64, k0 = blockIdx.y * 64;
  int t = threadIdx.x;
  for (int pass = 0; pass < 2; ++pass) {
    const u16* S = pass ? Sl : Sh;
    u16* D = pass ? Dl : Dh;
    for (int ch = t; ch < 512; ch += 256) {
      int r = ch >> 3, c0 = (ch & 7) * 8;
      *reinterpret_cast<uint4*>(&tile[r][c0]) =
          *reinterpret_cast<const uint4*>(S + (size_t)(x0 + r) * KC + k0 + c0);
    }
    __syncthreads();
    for (int ch = t; ch < 512; ch += 256) {
      int kr = ch >> 3, c0 = (ch & 7) * 8;
      union { u16 u[8]; uint4 v; } pk;
#pragma unroll
      for (int j = 0; j < 8; ++j) pk.u[j] = tile[c0 + j][kr];
      *reinterpret_cast<uint4*>(D + (size_t)(k0 + kr) * NP + x0 + c0) = pk.v;
    }
    __syncthreads();
  }
}

// im2col directly transposed + split: BimT hi/lo [xy][KC]
__global__ void k_im2colT(const float* __restrict__ fm, u16* __restrict__ base) {
  int ch = blockIdx.x * 256 + threadIdx.x;
  if (ch >= BSZ * WH * 72) return;
  int b = ch / (WH * 72);
  int rem = ch - b * WH * 72;
  int xy = rem / 72, kp = rem - xy * 72;
  int x = xy >> 6, y = xy & 63;
  union { u16 u[8]; uint4 v; } H, L;
#pragma unroll
  for (int j = 0; j < 8; ++j) {
    int k = kp * 8 + j;
    int c = k / 9, p = k - c * 9;
    int xi = x + p / 3 - 1, yj = y + p % 3 - 1;
    float v = 0.f;
    if (xi >= 0 && xi < WD && yj >= 0 && yj < WD)
      v = fm[((size_t)(b * C + c)) * WH + (xi << 6) + yj];
    split2(v, H.u[j], L.u[j]);
  }
  u16* bh = base + (size_t)b * 2 * WH * KC;
  u16* bl = bh + (size_t)WH * KC;
  *reinterpret_cast<uint4*>(bh + (size_t)xy * KC + kp * 8) = H.v;
  *reinterpret_cast<uint4*>(bl + (size_t)xy * KC + kp * 8) = L.v;
}

// ---------------- MFMA GEMMs ----------------

// gemm1: cr[m][n] = Akc[m][:] . BimT[n][:]   M-tile 128, N-tile 64, K=576
__global__ __launch_bounds__(256, 4) void k_gemmA(
    const u16* __restrict__ Ah, const u16* __restrict__ Al,
    const u16* __restrict__ Bh, const u16* __restrict__ Bl,
    const int* __restrict__ nliv, float* __restrict__ Cp) {
  int nl = *nliv;
  int m0 = blockIdx.y * 128;
  if (m0 >= nl) return;
  int n0 = blockIdx.x * 64;
  __shared__ __align__(16) u16 As[2][128][40];
  __shared__ __align__(16) u16 Bs[2][64][40];
  int t = threadIdx.x;
  f32x4 zero = {0.f, 0.f, 0.f, 0.f};
  f32x4 acc[2][4];
#pragma unroll
  for (int r = 0; r < 2; ++r)
#pragma unroll
    for (int c = 0; c < 4; ++c) acc[r][c] = zero;
  int l = t & 63, w = t >> 6;
  int lr = l & 15, lk = (l >> 4) * 8;
  for (int k0 = 0; k0 < KC; k0 += 32) {
    __syncthreads();
    for (int ch = t; ch < 1536; ch += 256) {
      const u16* src;
      u16* dst;
      if (ch < 1024) {
        int hl = ch >> 9, r = (ch >> 2) & 127, p = ch & 3;
        src = (hl ? Al : Ah) + (size_t)(m0 + r) * KC + k0 + p * 8;
        dst = &As[hl][r][p * 8];
      } else {
        int c2 = ch - 1024;
        int hl = c2 >> 8, r = (c2 >> 2) & 63, p = c2 & 3;
        src = (hl ? Bl : Bh) + (size_t)(n0 + r) * KC + k0 + p * 8;
        dst = &Bs[hl][r][p * 8];
      }
      *reinterpret_cast<uint4*>(dst) = *reinterpret_cast<const uint4*>(src);
    }
    __syncthreads();
    bf16x8 ah[2], al2[2], bh[4], bl2[4];
#pragma unroll
    for (int r = 0; r < 2; ++r) {
      ah[r] = *reinterpret_cast<const bf16x8*>(&As[0][32 * w + 16 * r + lr][lk]);
      al2[r] = *reinterpret_cast<const bf16x8*>(&As[1][32 * w + 16 * r + lr][lk]);
    }
#pragma unroll
    for (int c = 0; c < 4; ++c) {
      bh[c] = *reinterpret_cast<const bf16x8*>(&Bs[0][16 * c + lr][lk]);
      bl2[c] = *reinterpret_cast<const bf16x8*>(&Bs[1][16 * c + lr][lk]);
    }
#pragma unroll
    for (int r = 0; r < 2; ++r)
#pragma unroll
      for (int c = 0; c < 4; ++c) {
        acc[r][c] = __builtin_amdgcn_mfma_f32_16x16x32_bf16(ah[r], bh[c], acc[r][c], 0, 0, 0);
        acc[r][c] = __builtin_amdgcn_mfma_f32_16x16x32_bf16(ah[r], bl2[c], acc[r][c], 0, 0, 0);
        acc[r][c] = __builtin_amdgcn_mfma_f32_16x16x32_bf16(al2[r], bh[c], acc[r][c], 0, 0, 0);
      }
  }
#pragma unroll
  for (int r = 0; r < 2; ++r)
#pragma unroll
    for (int c = 0; c < 4; ++c)
#pragma unroll
      for (int q = 0; q < 4; ++q) {
        int row = m0 + 32 * w + 16 * r + ((l >> 4) << 2) + q;
        Cp[(size_t)row * WH + n0 + 16 * c + lr] = acc[r][c][q];
      }
}

// gemm2 v2: P[m][n] = sum_k AkT[m][k] * attT[n][k]  (both K-major, like gemmA)
__global__ __launch_bounds__(256, 4) void k_gemmB2(
    const u16* __restrict__ Ah, const u16* __restrict__ Al,
    const u16* __restrict__ Bh, const u16* __restrict__ Bl,
    const int* __restrict__ nliv, float* __restrict__ Cp) {
  int nl = *nliv;
  int Kend = (nl + 31) & ~31;
  int m0 = blockIdx.y * 64;
  int n0 = blockIdx.x * 64;
  __shared__ __align__(16) u16 As[2][64][40];
  __shared__ __align__(16) u16 Bs[2][64][40];
  int t = threadIdx.x;
  f32x4 zero = {0.f, 0.f, 0.f, 0.f};
  f32x4 acc[4];
#pragma unroll
  for (int c = 0; c < 4; ++c) acc[c] = zero;
  int l = t & 63, w = t >> 6;
  int lr = l & 15, lk = (l >> 4) * 8;
  for (int k0 = 0; k0 < Kend; k0 += 32) {
    __syncthreads();
    for (int ch = t; ch < 1024; ch += 256) {
      int sel = ch >> 9;  // 0: A(AkT), 1: B(attT)
      int c2 = ch & 511;
      int hl = c2 >> 8, r = (c2 >> 2) & 63, p = c2 & 3;
      const u16* src = sel ? ((hl ? Bl : Bh) + (size_t)(n0 + r) * NP + k0 + p * 8)
                           : ((hl ? Al : Ah) + (size_t)(m0 + r) * NP + k0 + p * 8);
      u16* dst = sel ? &Bs[hl][r][p * 8] : &As[hl][r][p * 8];
      *reinterpret_cast<uint4*>(dst) = *reinterpret_cast<const uint4*>(src);
    }
    __syncthreads();
    bf16x8 ah, al2, bh[4], bl2[4];
    ah = *reinterpret_cast<const bf16x8*>(&As[0][16 * w + lr][lk]);
    al2 = *reinterpret_cast<const bf16x8*>(&As[1][16 * w + lr][lk]);
#pragma unroll
    for (int c = 0; c < 4; ++c) {
      bh[c] = *reinterpret_cast<const bf16x8*>(&Bs[0][16 * c + lr][lk]);
      bl2[c] = *reinterpret_cast<const bf16x8*>(&Bs[1][16 * c + lr][lk]);
    }
#pragma unroll
    for (int c = 0; c < 4; ++c) {
      acc[c] = __builtin_amdgcn_mfma_f32_16x16x32_bf16(ah, bh[c], acc[c], 0, 0, 0);
      acc[c] = __builtin_amdgcn_mfma_f32_16x16x32_bf16(ah, bl2[c], acc[c], 0, 0, 0);
      acc[c] = __builtin_amdgcn_mfma_f32_16x16x32_bf16(al2, bh[c], acc[c], 0, 0, 0);
    }
  }
#pragma unroll
  for (int c = 0; c < 4; ++c)
#pragma unroll
    for (int q = 0; q < 4; ++q) {
      int row = m0 + 16 * w + ((l >> 4) << 2) + q;
      Cp[(size_t)row * WH + n0 + 16 * c + lr] = acc[c][q];
    }
}

// gemm2 fallback (packed att in cr, in-LDS transpose) — round-10 version
__global__ __launch_bounds__(256, 4) void k_gemmB(
    const u16* __restrict__ Ah, const u16* __restrict__ Al,
    const u32* __restrict__ att32, const int* __restrict__ nliv,
    float* __restrict__ Cp) {
  int nl = *nliv;
  int Kend = (nl + 31) & ~31;
  int m0 = blockIdx.y * 64;
  int n0 = blockIdx.x * 64;
  __shared__ __align__(16) u16 As[2][64][40];
  __shared__ __align__(16) u16 Bs[2][64][40];
  __shared__ __align__(16) u32 Bfu[32][70];
  int t = threadIdx.x;
  f32x4 zero = {0.f, 0.f, 0.f, 0.f};
  f32x4 acc[4];
#pragma unroll
  for (int c = 0; c < 4; ++c) acc[c] = zero;
  int l = t & 63, w = t >> 6;
  int lr = l & 15, lk = (l >> 4) * 8;
  for (int k0 = 0; k0 < Kend; k0 += 32) {
    __syncthreads();
    for (int ch = t; ch < 512; ch += 256) {
      int hl = ch >> 8, r = (ch >> 2) & 63, p = ch & 3;
      const u16* src = (hl ? Al : Ah) + (size_t)(m0 + r) * NP + k0 + p * 8;
      *reinterpret_cast<uint4*>(&As[hl][r][p * 8]) = *reinterpret_cast<const uint4*>(src);
    }
    {
      int r = t >> 3, c0 = (t & 7) * 8;
      int krow = k0 + r;
      uint4 w0 = {0u, 0u, 0u, 0u}, w1 = {0u, 0u, 0u, 0u};
      if (krow < nl) {
        const u32* bp = att32 + (size_t)krow * WH + n0 + c0;
        w0 = *reinterpret_cast<const uint4*>(bp);
        w1 = *reinterpret_cast<const uint4*>(bp + 4);
      }
      Bfu[r][c0 + 0] = w0.x; Bfu[r][c0 + 1] = w0.y;
      Bfu[r][c0 + 2] = w0.z; Bfu[r][c0 + 3] = w0.w;
      Bfu[r][c0 + 4] = w1.x; Bfu[r][c0 + 5] = w1.y;
      Bfu[r][c0 + 6] = w1.z; Bfu[r][c0 + 7] = w1.w;
    }
    __syncthreads();
    {
      int n = t >> 2, kq = (t & 3) * 8;
      union { u16 u[8]; uint4 v; } H, L;
#pragma unroll
      for (int j = 0; j < 8; ++j) {
        u32 v = Bfu[kq + j][n];
        H.u[j] = (u16)(v >> 16);
        L.u[j] = (u16)(v & 0xFFFFu);
      }
      *reinterpret_cast<uint4*>(&Bs[0][n][kq]) = H.v;
      *reinterpret_cast<uint4*>(&Bs[1][n][kq]) = L.v;
    }
    __syncthreads();
    bf16x8 ah, al2, bh[4], bl2[4];
    ah = *reinterpret_cast<const bf16x8*>(&As[0][16 * w + lr][lk]);
    al2 = *reinterpret_cast<const bf16x8*>(&As[1][16 * w + lr][lk]);
#pragma unroll
    for (int c = 0; c < 4; ++c) {
      bh[c] = *reinterpret_cast<const bf16x8*>(&Bs[0][16 * c + lr][lk]);
      bl2[c] = *reinterpret_cast<const bf16x8*>(&Bs[1][16 * c + lr][lk]);
    }
#pragma unroll
    for (int c = 0; c < 4; ++c) {
      acc[c] = __builtin_amdgcn_mfma_f32_16x16x32_bf16(ah, bh[c], acc[c], 0, 0, 0);
      acc[c] = __builtin_amdgcn_mfma_f32_16x16x32_bf16(ah, bl2[c], acc[c], 0, 0, 0);
      acc[c] = __builtin_amdgcn_mfma_f32_16x16x32_bf16(al2, bh[c], acc[c], 0, 0, 0);
    }
  }
#pragma unroll
  for (int c = 0; c < 4; ++c)
#pragma unroll
    for (int q = 0; q < 4; ++q) {
      int row = m0 + 16 * w + ((l >> 4) << 2) + q;
      Cp[(size_t)row * WH + n0 + 16 * c + lr] = acc[c][q];
    }
}

// ---------------- box / softmax / rec ----------------

__global__ __launch_bounds__(256) void k_box(const int* __restrict__ nliv,
                                             float* __restrict__ cr) {
  if ((int)blockIdx.x >= *nliv) return;
  __shared__ __align__(16) float sIn[WH];
  __shared__ __align__(16) float sT[WH];
  float* row = cr + (size_t)blockIdx.x * WH;
  const float4* r4 = reinterpret_cast<const float4*>(row);
  float4* s4 = reinterpret_cast<float4*>(sIn);
  for (int i = threadIdx.x; i < WH / 4; i += 256) s4[i] = r4[i];
  __syncthreads();
  for (int i = threadIdx.x; i < WH; i += 256) {
    int y = i & 63;
    float v = sIn[i];
    if (y > 0) v += sIn[i - 1];
    if (y < 63) v += sIn[i + 1];
    sT[i] = v;
  }
  __syncthreads();
  for (int i = threadIdx.x; i < WH; i += 256) {
    int x = i >> 6;
    float v = sT[i];
    if (x > 0) v += sT[i - 64];
    if (x < 63) v += sT[i + 64];
    row[i] = v;
  }
}

__global__ __launch_bounds__(256) void k_colstat(const float* __restrict__ cr,
                                                 const int* __restrict__ nliv,
                                                 float* __restrict__ pmax,
                                                 float* __restrict__ psum) {
  int xy = blockIdx.x * 256 + threadIdx.x;
  int nl = *nliv;
  int ns = (nl + 15) >> 4;
  int r0 = blockIdx.y * ns;
  int r1 = min(r0 + ns, nl);
  float mx = -3.4e38f, s = 0.f;
  for (int r = r0; r < r1; ++r) {
    float v = cr[(size_t)r * WH + xy];
    if (v <= mx) {
      s += __expf(v - mx);
    } else {
      s = s * __expf(mx - v) + 1.f;
      mx = v;
    }
  }
  pmax[blockIdx.y * WH + xy] = mx;
  psum[blockIdx.y * WH + xy] = s;
}

__global__ __launch_bounds__(256) void k_colmerge(const int* __restrict__ nliv,
                                                  const float* __restrict__ pmax,
                                                  const float* __restrict__ psum,
                                                  float* __restrict__ m2g,
                                                  float* __restrict__ invg) {
  int xy = blockIdx.x * 256 + threadIdx.x;
  int nl = *nliv;
  float M = -3.4e38f;
  for (int k = 0; k < 16; ++k) M = fmaxf(M, pmax[k * WH + xy]);
  float S = 0.f;
  if (M > -3.0e38f)
    for (int k = 0; k < 16; ++k) S += psum[k * WH + xy] * __expf(pmax[k * WH + xy] - M);
  int nm = NP - nl;
  float m2 = (nm > 0) ? fmaxf(M, 0.f) : M;
  float denom = (M > -3.0e38f ? S * __expf(M - m2) : 0.f) + (float)nm * __expf(-m2);
  m2g[xy] = m2;
  invg[xy] = 1.f / denom;
}

// transpose-apply: attT[plane][xy][n] = split(exp(cr[n][xy]-m2)*inv); zero pads.
__global__ __launch_bounds__(256) void k_applyT(const int* __restrict__ nliv,
                                                const float* __restrict__ m2g,
                                                const float* __restrict__ invg,
                                                const float* __restrict__ cr,
                                                u16* __restrict__ attT) {
  int nl = *nliv;
  int Kend = (nl + 31) & ~31;
  int n0 = blockIdx.y * 64;
  if (n0 >= Kend) return;
  int x0 = blockIdx.x * 64;
  __shared__ u16 Lh[64][65], Ll[64][65];
  __shared__ float sm2[64], sinv[64];
  int t = threadIdx.x;
  if (t < 64) {
    sm2[t] = m2g[x0 + t];
    sinv[t] = invg[x0 + t];
  }
  __syncthreads();
  for (int e = t; e < 4096; e += 256) {
    int i = e >> 6, j = e & 63;
    float v = 0.f;
    if (n0 + i < nl)
      v = __expf(cr[(size_t)(n0 + i) * WH + x0 + j] - sm2[j]) * sinv[j];
    u16 h, l;
    split2(v, h, l);
    Lh[i][j] = h;
    Ll[i][j] = l;
  }
  __syncthreads();
  u16* p0 = attT;
  u16* p1 = attT + (size_t)WH * NP;
  for (int e = t; e < 4096; e += 256) {
    int a = e >> 6, b2 = e & 63;
    p0[(size_t)(x0 + a) * NP + n0 + b2] = Lh[b2][a];
    p1[(size_t)(x0 + a) * NP + n0 + b2] = Ll[b2][a];
  }
}

// apply fallback: packed u32 in place over cr (round-10)
__global__ __launch_bounds__(256) void k_apply(const int* __restrict__ nliv,
                                               const float* __restrict__ m2g,
                                               const float* __restrict__ invg,
                                               float* __restrict__ cr) {
  int i = blockIdx.x * 256 + threadIdx.x;
  int row = i >> 10;
  int nl = *nliv;
  int kend = (nl + 31) & ~31;
  if (row >= kend) return;
  float4* p = reinterpret_cast<float4*>(cr) + i;
  uint4* po = reinterpret_cast<uint4*>(cr) + i;
  if (row >= nl) {
    *po = make_uint4(0u, 0u, 0u, 0u);
    return;
  }
  int xy = (i & 1023) << 2;
  float4 v = *p;
  const float4 m2 = *reinterpret_cast<const float4*>(m2g + xy);
  const float4 iv = *reinterpret_cast<const float4*>(invg + xy);
  uint4 o;
  o.x = pack2(__expf(v.x - m2.x) * iv.x);
  o.y = pack2(__expf(v.y - m2.y) * iv.y);
  o.z = pack2(__expf(v.z - m2.z) * iv.z);
  o.w = pack2(__expf(v.w - m2.w) * iv.w);
  *po = o;
}

__global__ void k_rec(const float* __restrict__ P, float* __restrict__ out) {
  int idx = blockIdx.x * 256 + threadIdx.x;
  if (idx >= BSZ * C * WH) return;
  int b = idx >> 18;
  int r = idx & 262143;
  int c = r >> 12;
  int xy = r & 4095;
  int x = xy >> 6, y = xy & 63;
  const float* Pb = P + (size_t)b * KC * WH;
  float acc = 0.f;
#pragma unroll
  for (int i = 0; i < 3; ++i) {
    int xp = x + 1 - i;
    if (xp < 0 || xp >= WD) continue;
#pragma unroll
    for (int j = 0; j < 3; ++j) {
      int yp = y + 1 - j;
      if (yp < 0 || yp >= WD) continue;
      acc += Pb[(size_t)(c * 9 + i * 3 + j) * WH + xp * WD + yp];
    }
  }
  out[idx] = acc;
}

// ---------------- launcher ----------------

extern "C" void kernel_launch(void* const* d_in, const int* in_sizes, int n_in,
                              void* d_out, int out_size, void* d_ws, size_t ws_size,
                              hipStream_t stream) {
  const float* fg    = (const float*)d_in[0];
  const float* mask  = (const float*)d_in[1];
  const float* Wv_f  = (const float*)d_in[7];
  const float* bv_f  = (const float*)d_in[8];
  const float* Wv_p  = (const float*)d_in[13];
  const float* bv_p  = (const float*)d_in[14];
  const float* gamma = (const float*)d_in[15];

  float* ws = (float*)d_ws;
  size_t off = 0;
  auto alloc = [&](size_t n) { size_t o = off; off += (n + 63) & ~(size_t)63; return o; };
  u16* AkcH = (u16*)(ws + alloc((size_t)BSZ * NP * KC / 2));
  u16* AkcL = (u16*)(ws + alloc((size_t)BSZ * NP * KC / 2));
  u16* AkTH = (u16*)(ws + alloc((size_t)KC * NP / 2));
  u16* AkTL = (u16*)(ws + alloc((size_t)KC * NP / 2));
  float* BimTPb = ws + alloc((size_t)BSZ * KC * WH);  // per-sample: [hi|lo] shorts == Pb f32
  float* mmf  = ws + alloc((size_t)BSZ * NP);
  int* lividx = (int*)(ws + alloc((size_t)BSZ * NP));
  int* nliv   = (int*)(ws + alloc(64));
  float* mu   = ws + alloc(BSZ * C);
  float* vmn  = ws + alloc(BSZ * C);
  float* pmax = ws + alloc((size_t)16 * WH);
  float* psum = ws + alloc((size_t)16 * WH);
  float* m2g  = ws + alloc(WH);
  float* invg = ws + alloc(WH);
  float* cr   = ws + alloc((size_t)NP * WH);  // single sample
  // attT (hi/lo u16 planes, [2][WH][NP]) allocated last; used only if it fits.
  size_t attT_off = alloc((size_t)WH * NP);
  float* attT_f = ws + attT_off;
  bool big = (off * sizeof(float)) <= ws_size;
  // prep fields alias head of cr (dead before gemmA writes cr)
  size_t poff = 0;
  auto palloc = [&](size_t n) { size_t o = poff; poff += (n + 63) & ~(size_t)63; return o; };
  float* bgp = cr + palloc((size_t)BSZ * PP * C);
  float* Vg  = cr + palloc((size_t)BSZ * PP * C);
  float* fmb = cr + palloc((size_t)BSZ * C * WH);
  (void)in_sizes; (void)n_in; (void)out_size;

  k_mu<<<BSZ * C, 256, 0, stream>>>(fg, mask, mu);
  k_vmean<<<1, 128, 0, stream>>>(Wv_f, bv_f, mu, vmn);
  k_fm<<<(BSZ * C * WH + 255) / 256, 256, 0, stream>>>(fg, mask, vmn, fmb);
  k_bgpT<<<dim3(PW, BSZ), 256, 0, stream>>>(fg, mask, bgp);
  k_vgT<<<(BSZ * PP + 3) / 4, 256, 0, stream>>>(bgp, Wv_p, bv_p, Vg);
  k_mmf<<<(BSZ * NP + 255) / 256, 256, 0, stream>>>(mask, mmf);
  k_scan<<<BSZ, 256, 0, stream>>>(mmf, lividx, nliv);
  k_ck<<<dim3(NP, BSZ), 64, 0, stream>>>(Vg, lividx, nliv, gamma, AkcH, AkcL);
  k_im2colT<<<(BSZ * WH * 72 + 255) / 256, 256, 0, stream>>>(fmb, (u16*)BimTPb);

  for (int b = 0; b < BSZ; ++b) {
    const u16* AkcHb = AkcH + (size_t)b * NP * KC;
    const u16* AkcLb = AkcL + (size_t)b * NP * KC;
    const u16* BimTh = (const u16*)BimTPb + (size_t)b * 2 * WH * KC;
    const u16* BimTl = BimTh + (size_t)WH * KC;
    float* Pb = BimTPb + (size_t)b * KC * WH;
    const int* nlb = nliv + b;
    k_trA<<<dim3(NP / 64, KC / 64), 256, 0, stream>>>(AkcHb, AkcLb, AkTH, AkTL);
    k_gemmA<<<dim3(WH / 64, NP / 128), 256, 0, stream>>>(AkcHb, AkcLb, BimTh, BimTl,
                                                         nlb, cr);
    k_box<<<NP, 256, 0, stream>>>(nlb, cr);
    k_colstat<<<dim3(WH / 256, 16), 256, 0, stream>>>(cr, nlb, pmax, psum);
    k_colmerge<<<WH / 256, 256, 0, stream>>>(nlb, pmax, psum, m2g, invg);
    if (big) {
      k_applyT<<<dim3(WH / 64, NP / 64), 256, 0, stream>>>(nlb, m2g, invg, cr,
                                                           (u16*)attT_f);
      k_gemmB2<<<dim3(WH / 64, KC / 64), 256, 0, stream>>>(
          AkTH, AkTL, (u16*)attT_f, (u16*)attT_f + (size_t)WH * NP, nlb, Pb);
    } else {
      k_apply<<<NP * (WH / 4) / 256, 256, 0, stream>>>(nlb, m2g, invg, cr);
      k_gemmB<<<dim3(WH / 64, KC / 64), 256, 0, stream>>>(AkTH, AkTL, (const u32*)cr,
                                                          nlb, Pb);
    }
  }
  k_rec<<<(BSZ * C * WH + 255) / 256, 256, 0, stream>>>(BimTPb, (float*)d_out);
}

// Round 13
// 717.575 us; speedup vs baseline: 1.1323x; 1.1323x over previous
//
#include <hip/hip_runtime.h>

// GLA forward. Structure:
//  - MPGA collapses: fm = mask ? fg : (Wv_f @ mean(bg) + bv_f)
//  - live patches (3x3 mask window == 0): GAP energy uniform ->
//    ck = (gamma/9) * Vg window, L2-normalized.
//  - compaction: only nlive rows flow through gemm1/box/softmax/gemm2.
//  - GEMMs: split-bf16 MFMA (hi/lo, 3 products) on v_mfma_f32_16x16x32_bf16.
//  - gemm2 is SPLIT-K (4 ways, partial planes aliased into dead cr, then
//    deterministic k_red4 sum): 576 -> 2304 blocks fixes the latency-bound
//    2.25-blocks/CU regime seen in rounds 8-11 (MfmaUtil 11%, all pipes idle).

#define BSZ 2
#define C 64
#define WD 64
#define WH 4096
#define PW 66
#define PP 4356
#define KC 576
#define NP 4096
#define SK 4

typedef unsigned short u16;
typedef unsigned int u32;
typedef short bf16x8 __attribute__((ext_vector_type(8)));
typedef float f32x4 __attribute__((ext_vector_type(4)));

__device__ inline u16 bf16_rne(float x) {
  unsigned u = __float_as_uint(x);
  return (u16)((u + 0x7FFFu + ((u >> 16) & 1u)) >> 16);
}
__device__ inline float bf16_tof(u16 h) { return __uint_as_float(((unsigned)h) << 16); }
__device__ inline void split2(float x, u16& h, u16& l) {
  h = bf16_rne(x);
  l = bf16_rne(x - bf16_tof(h));
}
__device__ inline u32 pack2(float x) {
  u16 h, l;
  split2(x, h, l);
  return ((u32)h << 16) | (u32)l;
}

// ---------------- prep ----------------

__global__ void k_mu(const float* __restrict__ fg, const float* __restrict__ mask,
                     float* __restrict__ mu) {
  int bc = blockIdx.x;
  int b = bc >> 6;
  const float* f = fg + (size_t)bc * WH;
  const float* mk = mask + (size_t)b * WH;
  float sum = 0.f;
  for (int i = threadIdx.x; i < WH; i += 256) sum += f[i] * (1.f - mk[i]);
  __shared__ float red[256];
  red[threadIdx.x] = sum;
  __syncthreads();
  for (int s = 128; s > 0; s >>= 1) {
    if (threadIdx.x < s) red[threadIdx.x] += red[threadIdx.x + s];
    __syncthreads();
  }
  if (threadIdx.x == 0) mu[bc] = red[0] / (float)WH;
}

__global__ void k_vmean(const float* __restrict__ Wv_f, const float* __restrict__ bv_f,
                        const float* __restrict__ mu, float* __restrict__ vmean) {
  int t = threadIdx.x;
  int b = t >> 6, c = t & 63;
  float acc = bv_f[c];
  for (int cc = 0; cc < C; ++cc) acc += Wv_f[c * C + cc] * mu[b * C + cc];
  vmean[t] = acc;
}

__global__ void k_fm(const float* __restrict__ fg, const float* __restrict__ mask,
                     const float* __restrict__ vmean, float* __restrict__ fm) {
  int idx = blockIdx.x * 256 + threadIdx.x;
  if (idx >= BSZ * C * WH) return;
  int b = idx >> 18;
  int c = (idx >> 12) & 63;
  int pos = idx & (WH - 1);
  float m = mask[b * WH + pos];
  fm[idx] = fg[idx] * m + (1.f - m) * vmean[b * C + c];
}

// bgp[b][pos][c] = padded background + 1e-7
__global__ void k_bgpT(const float* __restrict__ fg, const float* __restrict__ mask,
                       float* __restrict__ bgp) {
  int b = blockIdx.y, xp = blockIdx.x;
  float* out = bgp + ((size_t)b * PP + (size_t)xp * PW) * C;
  int t = threadIdx.x;
  __shared__ float tile[64][65];
  int xi = xp - 1;
  if (xi >= 0 && xi < WD) {
    const float* fgb = fg + (size_t)b * C * WH + (size_t)xi * WD;
    const float* mkb = mask + (size_t)b * WH + (size_t)xi * WD;
    for (int i = t; i < 64 * 64; i += 256) {
      int c = i >> 6, y = i & 63;
      tile[c][y] = fgb[(size_t)c * WH + y] * (1.f - mkb[y]);
    }
  }
  __syncthreads();
  for (int i = t; i < PW * C; i += 256) {
    int yp = i >> 6, c = i & 63;
    float v = 1e-7f;
    int yj = yp - 1;
    if (xi >= 0 && xi < WD && yj >= 0 && yj < WD) v += tile[c][yj];
    out[(size_t)yp * C + c] = v;
  }
}

// Vg[b][pos][o] = Wv_p @ bgp[pos,:] + bv_p
__global__ void k_vgT(const float* __restrict__ bgp, const float* __restrict__ Wv_p,
                      const float* __restrict__ bv_p, float* __restrict__ Vg) {
  __shared__ float Wt[64][65];
  __shared__ float bgl[4][64];
  int t = threadIdx.x;
  for (int i = t; i < 4096; i += 256) Wt[i & 63][i >> 6] = Wv_p[i];
  int pos0 = blockIdx.x * 4;
  {
    int p2 = t >> 6, c = t & 63;
    int gp = pos0 + p2;
    bgl[p2][c] = (gp < BSZ * PP) ? bgp[(size_t)gp * C + c] : 0.f;
  }
  __syncthreads();
  int pi = t >> 6, o = t & 63;
  int gpos = pos0 + pi;
  if (gpos < BSZ * PP) {
    float acc = bv_p[o];
    for (int c = 0; c < 64; ++c) acc += Wt[c][o] * bgl[pi][c];
    Vg[(size_t)gpos * C + o] = acc;
  }
}

// mmf[b][n] = 1 if 3x3 mask window all zero
__global__ void k_mmf(const float* __restrict__ mask, float* __restrict__ mmf) {
  int idx = blockIdx.x * 256 + threadIdx.x;
  if (idx >= BSZ * NP) return;
  int b = idx >> 12, n = idx & 4095;
  int x = n >> 6, y = n & 63;
  float z = 0.f;
  for (int di = -1; di <= 1; ++di)
    for (int dj = -1; dj <= 1; ++dj) {
      int xi = x + di, yj = y + dj;
      if (xi >= 0 && xi < WD && yj >= 0 && yj < WD) z += mask[b * WH + xi * WD + yj];
    }
  mmf[idx] = (z == 0.f) ? 1.f : 0.f;
}

__global__ void k_scan(const float* __restrict__ mmf, int* __restrict__ lividx,
                       int* __restrict__ nliv) {
  int b = blockIdx.x, t = threadIdx.x;
  const float* mm = mmf + (size_t)b * NP;
  int* li = lividx + (size_t)b * NP;
  __shared__ int cnt[256];
  int loc[16];
  int c = 0;
#pragma unroll
  for (int i = 0; i < 16; ++i) {
    int lv = (mm[t * 16 + i] != 0.f) ? 1 : 0;
    loc[i] = lv;
    c += lv;
  }
  cnt[t] = c;
  __syncthreads();
  for (int s = 1; s < 256; s <<= 1) {
    int v = (t >= s) ? cnt[t - s] : 0;
    __syncthreads();
    cnt[t] += v;
    __syncthreads();
  }
  int base = cnt[t] - c;
#pragma unroll
  for (int i = 0; i < 16; ++i)
    if (loc[i]) li[base++] = t * 16 + i;
  int nl = cnt[255];
  if (t == 0) nliv[b] = nl;
  for (int i = nl + t; i < NP; i += 256) li[i] = 0;
}

// live-patch ck: (gamma/9)*Vg window, L2-normalized -> Akc hi/lo [nc][KC]
__global__ void k_ck(const float* __restrict__ Vg, const int* __restrict__ lividx,
                     const int* __restrict__ nliv, const float* __restrict__ gamma,
                     u16* __restrict__ AkcH, u16* __restrict__ AkcL) {
  int b = blockIdx.y, nc = blockIdx.x;
  if (nc >= nliv[b]) return;
  int n = lividx[(size_t)b * NP + nc];
  int x = n >> 6, y = n & 63;
  int c = threadIdx.x;
  const float* vg = Vg + (size_t)b * PP * C;
  float g9 = gamma[0] * (1.f / 9.f);
  float o[9];
  float ss = 0.f;
#pragma unroll
  for (int p = 0; p < 9; ++p) {
    int di = p / 3, dj = p % 3;
    float v = g9 * vg[(size_t)((x + di) * PW + (y + dj)) * C + c];
    o[p] = v;
    ss += v * v;
  }
#pragma unroll
  for (int off = 32; off > 0; off >>= 1) ss += __shfl_down(ss, off, 64);
  ss = __shfl(ss, 0, 64);
  float rn = 1.f / sqrtf(ss);
  u16* ph = AkcH + ((size_t)b * NP + nc) * KC + c * 9;
  u16* pl = AkcL + ((size_t)b * NP + nc) * KC + c * 9;
#pragma unroll
  for (int p = 0; p < 9; ++p) {
    u16 h, l;
    split2(o[p] * rn, h, l);
    ph[p] = h;
    pl[p] = l;
  }
}

// Akc [NP][KC] -> AkT [KC][NP] (hi/lo)
__global__ void k_trA(const u16* __restrict__ Sh, const u16* __restrict__ Sl,
                      u16* __restrict__ Dh, u16* __restrict__ Dl) {
  __shared__ __align__(16) u16 tile[64][72];
  int x0 = blockIdx.x * 64, k0 = blockIdx.y * 64;
  int t = threadIdx.x;
  for (int pass = 0; pass < 2; ++pass) {
    const u16* S = pass ? Sl : Sh;
    u16* D = pass ? Dl : Dh;
    for (int ch = t; ch < 512; ch += 256) {
      int r = ch >> 3, c0 = (ch & 7) * 8;
      *reinterpret_cast<uint4*>(&tile[r][c0]) =
          *reinterpret_cast<const uint4*>(S + (size_t)(x0 + r) * KC + k0 + c0);
    }
    __syncthreads();
    for (int ch = t; ch < 512; ch += 256) {
      int kr = ch >> 3, c0 = (ch & 7) * 8;
      union { u16 u[8]; uint4 v; } pk;
#pragma unroll
      for (int j = 0; j < 8; ++j) pk.u[j] = tile[c0 + j][kr];
      *reinterpret_cast<uint4*>(D + (size_t)(k0 + kr) * NP + x0 + c0) = pk.v;
    }
    __syncthreads();
  }
}

// im2col directly transposed + split: BimT hi/lo [xy][KC]
__global__ void k_im2colT(const float* __restrict__ fm, u16* __restrict__ base) {
  int ch = blockIdx.x * 256 + threadIdx.x;
  if (ch >= BSZ * WH * 72) return;
  int b = ch / (WH * 72);
  int rem = ch - b * WH * 72;
  int xy = rem / 72, kp = rem - xy * 72;
  int x = xy >> 6, y = xy & 63;
  union { u16 u[8]; uint4 v; } H, L;
#pragma unroll
  for (int j = 0; j < 8; ++j) {
    int k = kp * 8 + j;
    int c = k / 9, p = k - c * 9;
    int xi = x + p / 3 - 1, yj = y + p % 3 - 1;
    float v = 0.f;
    if (xi >= 0 && xi < WD && yj >= 0 && yj < WD)
      v = fm[((size_t)(b * C + c)) * WH + (xi << 6) + yj];
    split2(v, H.u[j], L.u[j]);
  }
  u16* bh = base + (size_t)b * 2 * WH * KC;
  u16* bl = bh + (size_t)WH * KC;
  *reinterpret_cast<uint4*>(bh + (size_t)xy * KC + kp * 8) = H.v;
  *reinterpret_cast<uint4*>(bl + (size_t)xy * KC + kp * 8) = L.v;
}

// ---------------- MFMA GEMMs ----------------

// gemm1: cr[m][n] = Akc[m][:] . BimT[n][:]   M-tile 128, N-tile 64, K=576
__global__ __launch_bounds__(256, 4) void k_gemmA(
    const u16* __restrict__ Ah, const u16* __restrict__ Al,
    const u16* __restrict__ Bh, const u16* __restrict__ Bl,
    const int* __restrict__ nliv, float* __restrict__ Cp) {
  int nl = *nliv;
  int m0 = blockIdx.y * 128;
  if (m0 >= nl) return;
  int n0 = blockIdx.x * 64;
  __shared__ __align__(16) u16 As[2][128][40];
  __shared__ __align__(16) u16 Bs[2][64][40];
  int t = threadIdx.x;
  f32x4 zero = {0.f, 0.f, 0.f, 0.f};
  f32x4 acc[2][4];
#pragma unroll
  for (int r = 0; r < 2; ++r)
#pragma unroll
    for (int c = 0; c < 4; ++c) acc[r][c] = zero;
  int l = t & 63, w = t >> 6;
  int lr = l & 15, lk = (l >> 4) * 8;
  for (int k0 = 0; k0 < KC; k0 += 32) {
    __syncthreads();
    for (int ch = t; ch < 1536; ch += 256) {
      const u16* src;
      u16* dst;
      if (ch < 1024) {
        int hl = ch >> 9, r = (ch >> 2) & 127, p = ch & 3;
        src = (hl ? Al : Ah) + (size_t)(m0 + r) * KC + k0 + p * 8;
        dst = &As[hl][r][p * 8];
      } else {
        int c2 = ch - 1024;
        int hl = c2 >> 8, r = (c2 >> 2) & 63, p = c2 & 3;
        src = (hl ? Bl : Bh) + (size_t)(n0 + r) * KC + k0 + p * 8;
        dst = &Bs[hl][r][p * 8];
      }
      *reinterpret_cast<uint4*>(dst) = *reinterpret_cast<const uint4*>(src);
    }
    __syncthreads();
    bf16x8 ah[2], al2[2], bh[4], bl2[4];
#pragma unroll
    for (int r = 0; r < 2; ++r) {
      ah[r] = *reinterpret_cast<const bf16x8*>(&As[0][32 * w + 16 * r + lr][lk]);
      al2[r] = *reinterpret_cast<const bf16x8*>(&As[1][32 * w + 16 * r + lr][lk]);
    }
#pragma unroll
    for (int c = 0; c < 4; ++c) {
      bh[c] = *reinterpret_cast<const bf16x8*>(&Bs[0][16 * c + lr][lk]);
      bl2[c] = *reinterpret_cast<const bf16x8*>(&Bs[1][16 * c + lr][lk]);
    }
#pragma unroll
    for (int r = 0; r < 2; ++r)
#pragma unroll
      for (int c = 0; c < 4; ++c) {
        acc[r][c] = __builtin_amdgcn_mfma_f32_16x16x32_bf16(ah[r], bh[c], acc[r][c], 0, 0, 0);
        acc[r][c] = __builtin_amdgcn_mfma_f32_16x16x32_bf16(ah[r], bl2[c], acc[r][c], 0, 0, 0);
        acc[r][c] = __builtin_amdgcn_mfma_f32_16x16x32_bf16(al2[r], bh[c], acc[r][c], 0, 0, 0);
      }
  }
#pragma unroll
  for (int r = 0; r < 2; ++r)
#pragma unroll
    for (int c = 0; c < 4; ++c)
#pragma unroll
      for (int q = 0; q < 4; ++q) {
        int row = m0 + 32 * w + 16 * r + ((l >> 4) << 2) + q;
        Cp[(size_t)row * WH + n0 + 16 * c + lr] = acc[r][c][q];
      }
}

// gemm2 split-K: Ppart[z][m][n] = sum_{k in split z} AkT[m][k] * attT[n][k]
__global__ __launch_bounds__(256, 4) void k_gemmB3(
    const u16* __restrict__ Ah, const u16* __restrict__ Al,
    const u16* __restrict__ Bh, const u16* __restrict__ Bl,
    const int* __restrict__ nliv, float* __restrict__ Ppart) {
  int nl = *nliv;
  int Kend = (nl + 31) & ~31;
  int steps = Kend >> 5;
  int cs = (steps + SK - 1) / SK;
  int kbeg = (int)blockIdx.z * cs * 32;
  int kfin = min(kbeg + cs * 32, Kend);
  int m0 = blockIdx.y * 64;
  int n0 = blockIdx.x * 64;
  __shared__ __align__(16) u16 As[2][64][40];
  __shared__ __align__(16) u16 Bs[2][64][40];
  int t = threadIdx.x;
  f32x4 zero = {0.f, 0.f, 0.f, 0.f};
  f32x4 acc[4];
#pragma unroll
  for (int c = 0; c < 4; ++c) acc[c] = zero;
  int l = t & 63, w = t >> 6;
  int lr = l & 15, lk = (l >> 4) * 8;
  for (int k0 = kbeg; k0 < kfin; k0 += 32) {
    __syncthreads();
    for (int ch = t; ch < 1024; ch += 256) {
      int sel = ch >> 9;  // 0: A(AkT), 1: B(attT)
      int c2 = ch & 511;
      int hl = c2 >> 8, r = (c2 >> 2) & 63, p = c2 & 3;
      const u16* src = sel ? ((hl ? Bl : Bh) + (size_t)(n0 + r) * NP + k0 + p * 8)
                           : ((hl ? Al : Ah) + (size_t)(m0 + r) * NP + k0 + p * 8);
      u16* dst = sel ? &Bs[hl][r][p * 8] : &As[hl][r][p * 8];
      *reinterpret_cast<uint4*>(dst) = *reinterpret_cast<const uint4*>(src);
    }
    __syncthreads();
    bf16x8 ah, al2, bh[4], bl2[4];
    ah = *reinterpret_cast<const bf16x8*>(&As[0][16 * w + lr][lk]);
    al2 = *reinterpret_cast<const bf16x8*>(&As[1][16 * w + lr][lk]);
#pragma unroll
    for (int c = 0; c < 4; ++c) {
      bh[c] = *reinterpret_cast<const bf16x8*>(&Bs[0][16 * c + lr][lk]);
      bl2[c] = *reinterpret_cast<const bf16x8*>(&Bs[1][16 * c + lr][lk]);
    }
#pragma unroll
    for (int c = 0; c < 4; ++c) {
      acc[c] = __builtin_amdgcn_mfma_f32_16x16x32_bf16(ah, bh[c], acc[c], 0, 0, 0);
      acc[c] = __builtin_amdgcn_mfma_f32_16x16x32_bf16(ah, bl2[c], acc[c], 0, 0, 0);
      acc[c] = __builtin_amdgcn_mfma_f32_16x16x32_bf16(al2, bh[c], acc[c], 0, 0, 0);
    }
  }
  float* Cp = Ppart + (size_t)blockIdx.z * KC * WH;
#pragma unroll
  for (int c = 0; c < 4; ++c)
#pragma unroll
    for (int q = 0; q < 4; ++q) {
      int row = m0 + 16 * w + ((l >> 4) << 2) + q;
      Cp[(size_t)row * WH + n0 + 16 * c + lr] = acc[c][q];
    }
}

// deterministic reduce of SK partial planes -> Pb
__global__ __launch_bounds__(256) void k_red4(const float* __restrict__ Pp,
                                              float* __restrict__ Pb) {
  int i = blockIdx.x * 256 + threadIdx.x;  // float4 index; KC*WH/4 exact
  const float4* p0 = reinterpret_cast<const float4*>(Pp) + i;
  const float4* p1 = reinterpret_cast<const float4*>(Pp + (size_t)KC * WH) + i;
  const float4* p2 = reinterpret_cast<const float4*>(Pp + (size_t)2 * KC * WH) + i;
  const float4* p3 = reinterpret_cast<const float4*>(Pp + (size_t)3 * KC * WH) + i;
  float4 a = *p0, b = *p1, c = *p2, d = *p3;
  float4 o;
  o.x = (a.x + b.x) + (c.x + d.x);
  o.y = (a.y + b.y) + (c.y + d.y);
  o.z = (a.z + b.z) + (c.z + d.z);
  o.w = (a.w + b.w) + (c.w + d.w);
  *(reinterpret_cast<float4*>(Pb) + i) = o;
}

// gemm2 fallback (packed att in cr, in-LDS transpose) — round-10 version
__global__ __launch_bounds__(256, 4) void k_gemmB(
    const u16* __restrict__ Ah, const u16* __restrict__ Al,
    const u32* __restrict__ att32, const int* __restrict__ nliv,
    float* __restrict__ Cp) {
  int nl = *nliv;
  int Kend = (nl + 31) & ~31;
  int m0 = blockIdx.y * 64;
  int n0 = blockIdx.x * 64;
  __shared__ __align__(16) u16 As[2][64][40];
  __shared__ __align__(16) u16 Bs[2][64][40];
  __shared__ __align__(16) u32 Bfu[32][70];
  int t = threadIdx.x;
  f32x4 zero = {0.f, 0.f, 0.f, 0.f};
  f32x4 acc[4];
#pragma unroll
  for (int c = 0; c < 4; ++c) acc[c] = zero;
  int l = t & 63, w = t >> 6;
  int lr = l & 15, lk = (l >> 4) * 8;
  for (int k0 = 0; k0 < Kend; k0 += 32) {
    __syncthreads();
    for (int ch = t; ch < 512; ch += 256) {
      int hl = ch >> 8, r = (ch >> 2) & 63, p = ch & 3;
      const u16* src = (hl ? Al : Ah) + (size_t)(m0 + r) * NP + k0 + p * 8;
      *reinterpret_cast<uint4*>(&As[hl][r][p * 8]) = *reinterpret_cast<const uint4*>(src);
    }
    {
      int r = t >> 3, c0 = (t & 7) * 8;
      int krow = k0 + r;
      uint4 w0 = {0u, 0u, 0u, 0u}, w1 = {0u, 0u, 0u, 0u};
      if (krow < nl) {
        const u32* bp = att32 + (size_t)krow * WH + n0 + c0;
        w0 = *reinterpret_cast<const uint4*>(bp);
        w1 = *reinterpret_cast<const uint4*>(bp + 4);
      }
      Bfu[r][c0 + 0] = w0.x; Bfu[r][c0 + 1] = w0.y;
      Bfu[r][c0 + 2] = w0.z; Bfu[r][c0 + 3] = w0.w;
      Bfu[r][c0 + 4] = w1.x; Bfu[r][c0 + 5] = w1.y;
      Bfu[r][c0 + 6] = w1.z; Bfu[r][c0 + 7] = w1.w;
    }
    __syncthreads();
    {
      int n = t >> 2, kq = (t & 3) * 8;
      union { u16 u[8]; uint4 v; } H, L;
#pragma unroll
      for (int j = 0; j < 8; ++j) {
        u32 v = Bfu[kq + j][n];
        H.u[j] = (u16)(v >> 16);
        L.u[j] = (u16)(v & 0xFFFFu);
      }
      *reinterpret_cast<uint4*>(&Bs[0][n][kq]) = H.v;
      *reinterpret_cast<uint4*>(&Bs[1][n][kq]) = L.v;
    }
    __syncthreads();
    bf16x8 ah, al2, bh[4], bl2[4];
    ah = *reinterpret_cast<const bf16x8*>(&As[0][16 * w + lr][lk]);
    al2 = *reinterpret_cast<const bf16x8*>(&As[1][16 * w + lr][lk]);
#pragma unroll
    for (int c = 0; c < 4; ++c) {
      bh[c] = *reinterpret_cast<const bf16x8*>(&Bs[0][16 * c + lr][lk]);
      bl2[c] = *reinterpret_cast<const bf16x8*>(&Bs[1][16 * c + lr][lk]);
    }
#pragma unroll
    for (int c = 0; c < 4; ++c) {
      acc[c] = __builtin_amdgcn_mfma_f32_16x16x32_bf16(ah, bh[c], acc[c], 0, 0, 0);
      acc[c] = __builtin_amdgcn_mfma_f32_16x16x32_bf16(ah, bl2[c], acc[c], 0, 0, 0);
      acc[c] = __builtin_amdgcn_mfma_f32_16x16x32_bf16(al2, bh[c], acc[c], 0, 0, 0);
    }
  }
#pragma unroll
  for (int c = 0; c < 4; ++c)
#pragma unroll
    for (int q = 0; q < 4; ++q) {
      int row = m0 + 16 * w + ((l >> 4) << 2) + q;
      Cp[(size_t)row * WH + n0 + 16 * c + lr] = acc[c][q];
    }
}

// ---------------- box / softmax / rec ----------------

__global__ __launch_bounds__(256) void k_box(const int* __restrict__ nliv,
                                             float* __restrict__ cr) {
  if ((int)blockIdx.x >= *nliv) return;
  __shared__ __align__(16) float sIn[WH];
  __shared__ __align__(16) float sT[WH];
  float* row = cr + (size_t)blockIdx.x * WH;
  const float4* r4 = reinterpret_cast<const float4*>(row);
  float4* s4 = reinterpret_cast<float4*>(sIn);
  for (int i = threadIdx.x; i < WH / 4; i += 256) s4[i] = r4[i];
  __syncthreads();
  for (int i = threadIdx.x; i < WH; i += 256) {
    int y = i & 63;
    float v = sIn[i];
    if (y > 0) v += sIn[i - 1];
    if (y < 63) v += sIn[i + 1];
    sT[i] = v;
  }
  __syncthreads();
  for (int i = threadIdx.x; i < WH; i += 256) {
    int x = i >> 6;
    float v = sT[i];
    if (x > 0) v += sT[i - 64];
    if (x < 63) v += sT[i + 64];
    row[i] = v;
  }
}

__global__ __launch_bounds__(256) void k_colstat(const float* __restrict__ cr,
                                                 const int* __restrict__ nliv,
                                                 float* __restrict__ pmax,
                                                 float* __restrict__ psum) {
  int xy = blockIdx.x * 256 + threadIdx.x;
  int nl = *nliv;
  int ns = (nl + 15) >> 4;
  int r0 = blockIdx.y * ns;
  int r1 = min(r0 + ns, nl);
  float mx = -3.4e38f, s = 0.f;
  for (int r = r0; r < r1; ++r) {
    float v = cr[(size_t)r * WH + xy];
    if (v <= mx) {
      s += __expf(v - mx);
    } else {
      s = s * __expf(mx - v) + 1.f;
      mx = v;
    }
  }
  pmax[blockIdx.y * WH + xy] = mx;
  psum[blockIdx.y * WH + xy] = s;
}

__global__ __launch_bounds__(256) void k_colmerge(const int* __restrict__ nliv,
                                                  const float* __restrict__ pmax,
                                                  const float* __restrict__ psum,
                                                  float* __restrict__ m2g,
                                                  float* __restrict__ invg) {
  int xy = blockIdx.x * 256 + threadIdx.x;
  int nl = *nliv;
  float M = -3.4e38f;
  for (int k = 0; k < 16; ++k) M = fmaxf(M, pmax[k * WH + xy]);
  float S = 0.f;
  if (M > -3.0e38f)
    for (int k = 0; k < 16; ++k) S += psum[k * WH + xy] * __expf(pmax[k * WH + xy] - M);
  int nm = NP - nl;
  float m2 = (nm > 0) ? fmaxf(M, 0.f) : M;
  float denom = (M > -3.0e38f ? S * __expf(M - m2) : 0.f) + (float)nm * __expf(-m2);
  m2g[xy] = m2;
  invg[xy] = 1.f / denom;
}

// transpose-apply: attT[plane][xy][n] = split(exp(cr[n][xy]-m2)*inv); zero pads.
__global__ __launch_bounds__(256) void k_applyT(const int* __restrict__ nliv,
                                                const float* __restrict__ m2g,
                                                const float* __restrict__ invg,
                                                const float* __restrict__ cr,
                                                u16* __restrict__ attT) {
  int nl = *nliv;
  int Kend = (nl + 31) & ~31;
  int n0 = blockIdx.y * 64;
  if (n0 >= Kend) return;
  int x0 = blockIdx.x * 64;
  __shared__ u16 Lh[64][65], Ll[64][65];
  __shared__ float sm2[64], sinv[64];
  int t = threadIdx.x;
  if (t < 64) {
    sm2[t] = m2g[x0 + t];
    sinv[t] = invg[x0 + t];
  }
  __syncthreads();
  for (int e = t; e < 4096; e += 256) {
    int i = e >> 6, j = e & 63;
    float v = 0.f;
    if (n0 + i < nl)
      v = __expf(cr[(size_t)(n0 + i) * WH + x0 + j] - sm2[j]) * sinv[j];
    u16 h, l;
    split2(v, h, l);
    Lh[i][j] = h;
    Ll[i][j] = l;
  }
  __syncthreads();
  u16* p0 = attT;
  u16* p1 = attT + (size_t)WH * NP;
  for (int e = t; e < 4096; e += 256) {
    int a = e >> 6, b2 = e & 63;
    p0[(size_t)(x0 + a) * NP + n0 + b2] = Lh[b2][a];
    p1[(size_t)(x0 + a) * NP + n0 + b2] = Ll[b2][a];
  }
}

// apply fallback: packed u32 in place over cr (round-10)
__global__ __launch_bounds__(256) void k_apply(const int* __restrict__ nliv,
                                               const float* __restrict__ m2g,
                                               const float* __restrict__ invg,
                                               float* __restrict__ cr) {
  int i = blockIdx.x * 256 + threadIdx.x;
  int row = i >> 10;
  int nl = *nliv;
  int kend = (nl + 31) & ~31;
  if (row >= kend) return;
  float4* p = reinterpret_cast<float4*>(cr) + i;
  uint4* po = reinterpret_cast<uint4*>(cr) + i;
  if (row >= nl) {
    *po = make_uint4(0u, 0u, 0u, 0u);
    return;
  }
  int xy = (i & 1023) << 2;
  float4 v = *p;
  const float4 m2 = *reinterpret_cast<const float4*>(m2g + xy);
  const float4 iv = *reinterpret_cast<const float4*>(invg + xy);
  uint4 o;
  o.x = pack2(__expf(v.x - m2.x) * iv.x);
  o.y = pack2(__expf(v.y - m2.y) * iv.y);
  o.z = pack2(__expf(v.z - m2.z) * iv.z);
  o.w = pack2(__expf(v.w - m2.w) * iv.w);
  *po = o;
}

__global__ void k_rec(const float* __restrict__ P, float* __restrict__ out) {
  int idx = blockIdx.x * 256 + threadIdx.x;
  if (idx >= BSZ * C * WH) return;
  int b = idx >> 18;
  int r = idx & 262143;
  int c = r >> 12;
  int xy = r & 4095;
  int x = xy >> 6, y = xy & 63;
  const float* Pb = P + (size_t)b * KC * WH;
  float acc = 0.f;
#pragma unroll
  for (int i = 0; i < 3; ++i) {
    int xp = x + 1 - i;
    if (xp < 0 || xp >= WD) continue;
#pragma unroll
    for (int j = 0; j < 3; ++j) {
      int yp = y + 1 - j;
      if (yp < 0 || yp >= WD) continue;
      acc += Pb[(size_t)(c * 9 + i * 3 + j) * WH + xp * WD + yp];
    }
  }
  out[idx] = acc;
}

// ---------------- launcher ----------------

extern "C" void kernel_launch(void* const* d_in, const int* in_sizes, int n_in,
                              void* d_out, int out_size, void* d_ws, size_t ws_size,
                              hipStream_t stream) {
  const float* fg    = (const float*)d_in[0];
  const float* mask  = (const float*)d_in[1];
  const float* Wv_f  = (const float*)d_in[7];
  const float* bv_f  = (const float*)d_in[8];
  const float* Wv_p  = (const float*)d_in[13];
  const float* bv_p  = (const float*)d_in[14];
  const float* gamma = (const float*)d_in[15];

  float* ws = (float*)d_ws;
  size_t off = 0;
  auto alloc = [&](size_t n) { size_t o = off; off += (n + 63) & ~(size_t)63; return o; };
  u16* AkcH = (u16*)(ws + alloc((size_t)BSZ * NP * KC / 2));
  u16* AkcL = (u16*)(ws + alloc((size_t)BSZ * NP * KC / 2));
  u16* AkTH = (u16*)(ws + alloc((size_t)KC * NP / 2));
  u16* AkTL = (u16*)(ws + alloc((size_t)KC * NP / 2));
  float* BimTPb = ws + alloc((size_t)BSZ * KC * WH);  // per-sample: [hi|lo] shorts == Pb f32
  float* mmf  = ws + alloc((size_t)BSZ * NP);
  int* lividx = (int*)(ws + alloc((size_t)BSZ * NP));
  int* nliv   = (int*)(ws + alloc(64));
  float* mu   = ws + alloc(BSZ * C);
  float* vmn  = ws + alloc(BSZ * C);
  float* pmax = ws + alloc((size_t)16 * WH);
  float* psum = ws + alloc((size_t)16 * WH);
  float* m2g  = ws + alloc(WH);
  float* invg = ws + alloc(WH);
  float* cr   = ws + alloc((size_t)NP * WH);  // single sample; split-K partials alias here
  // attT (hi/lo u16 planes, [2][WH][NP]) allocated last; used only if it fits.
  size_t attT_off = alloc((size_t)WH * NP);
  float* attT_f = ws + attT_off;
  bool big = (off * sizeof(float)) <= ws_size;
  // prep fields alias head of cr (dead before gemmA writes cr)
  size_t poff = 0;
  auto palloc = [&](size_t n) { size_t o = poff; poff += (n + 63) & ~(size_t)63; return o; };
  float* bgp = cr + palloc((size_t)BSZ * PP * C);
  float* Vg  = cr + palloc((size_t)BSZ * PP * C);
  float* fmb = cr + palloc((size_t)BSZ * C * WH);
  (void)in_sizes; (void)n_in; (void)out_size;

  k_mu<<<BSZ * C, 256, 0, stream>>>(fg, mask, mu);
  k_vmean<<<1, 128, 0, stream>>>(Wv_f, bv_f, mu, vmn);
  k_fm<<<(BSZ * C * WH + 255) / 256, 256, 0, stream>>>(fg, mask, vmn, fmb);
  k_bgpT<<<dim3(PW, BSZ), 256, 0, stream>>>(fg, mask, bgp);
  k_vgT<<<(BSZ * PP + 3) / 4, 256, 0, stream>>>(bgp, Wv_p, bv_p, Vg);
  k_mmf<<<(BSZ * NP + 255) / 256, 256, 0, stream>>>(mask, mmf);
  k_scan<<<BSZ, 256, 0, stream>>>(mmf, lividx, nliv);
  k_ck<<<dim3(NP, BSZ), 64, 0, stream>>>(Vg, lividx, nliv, gamma, AkcH, AkcL);
  k_im2colT<<<(BSZ * WH * 72 + 255) / 256, 256, 0, stream>>>(fmb, (u16*)BimTPb);

  for (int b = 0; b < BSZ; ++b) {
    const u16* AkcHb = AkcH + (size_t)b * NP * KC;
    const u16* AkcLb = AkcL + (size_t)b * NP * KC;
    const u16* BimTh = (const u16*)BimTPb + (size_t)b * 2 * WH * KC;
    const u16* BimTl = BimTh + (size_t)WH * KC;
    float* Pb = BimTPb + (size_t)b * KC * WH;
    const int* nlb = nliv + b;
    k_trA<<<dim3(NP / 64, KC / 64), 256, 0, stream>>>(AkcHb, AkcLb, AkTH, AkTL);
    k_gemmA<<<dim3(WH / 64, NP / 128), 256, 0, stream>>>(AkcHb, AkcLb, BimTh, BimTl,
                                                         nlb, cr);
    k_box<<<NP, 256, 0, stream>>>(nlb, cr);
    k_colstat<<<dim3(WH / 256, 16), 256, 0, stream>>>(cr, nlb, pmax, psum);
    k_colmerge<<<WH / 256, 256, 0, stream>>>(nlb, pmax, psum, m2g, invg);
    if (big) {
      k_applyT<<<dim3(WH / 64, NP / 64), 256, 0, stream>>>(nlb, m2g, invg, cr,
                                                           (u16*)attT_f);
      // cr is dead now -> reuse as SK partial planes
      k_gemmB3<<<dim3(WH / 64, KC / 64, SK), 256, 0, stream>>>(
          AkTH, AkTL, (u16*)attT_f, (u16*)attT_f + (size_t)WH * NP, nlb, cr);
      k_red4<<<(KC * WH / 4) / 256, 256, 0, stream>>>(cr, Pb);
    } else {
      k_apply<<<NP * (WH / 4) / 256, 256, 0, stream>>>(nlb, m2g, invg, cr);
      k_gemmB<<<dim3(WH / 64, KC / 64), 256, 0, stream>>>(AkTH, AkTL, (const u32*)cr,
                                                          nlb, Pb);
    }
  }
  k_rec<<<(BSZ * C * WH + 255) / 256, 256, 0, stream>>>(BimTPb, (float*)d_out);
}